// Round 1
// baseline (1715.193 us; speedup 1.0000x reference)
//
#include <hip/hip_runtime.h>
#include <math.h>

#define Bq 8
#define Lq 1024
#define Hq 8
#define Eq 64
#define ROWS 128   // q-rows (and threads) per block
#define KT 32      // keys per LDS tile

// slot -> source head, packed 4 bits each (slot0 lowest nibble):
// _PERM = [6,2,1,7,3,0,5,4]; SERIES_IDX = [2,1,7,3,0,5,4]; CROSS_IDX = [6]
// slots 0..6 = series heads {2,1,7,3,0,5,4}, slot 7 = cross head 6
#define SRC_HEAD_PACKED 0x64503712u

__global__ __launch_bounds__(ROWS, 2)
void attn_kernel(const float* __restrict__ Q, const float* __restrict__ Ks,
                 const float* __restrict__ KTs, const float* __restrict__ Vs,
                 const float* __restrict__ VTs, float* __restrict__ out) {
    const int qt   = blockIdx.x;      // q-tile index (0..7)
    const int slot = blockIdx.y;      // output head slot (0..7)
    const int b    = blockIdx.z;      // batch
    const int h    = (SRC_HEAD_PACKED >> (slot * 4)) & 0xF;
    const bool cross = (slot == 7);
    const float* __restrict__ Kp = cross ? KTs : Ks;
    const float* __restrict__ Vp = cross ? VTs : Vs;
    const int row = qt * ROWS + threadIdx.x;   // this thread's query row
    const float scale = 0.125f;                // 1/sqrt(64)

    // load q row into registers (contiguous 256 B per thread)
    float q[Eq];
    {
        const float4* qp = (const float4*)(Q + (((size_t)b * Lq + row) * Hq + h) * Eq);
        float4* q4 = (float4*)q;
        #pragma unroll
        for (int i = 0; i < Eq / 4; ++i) q4[i] = qp[i];
    }

    float O[Eq];
    #pragma unroll
    for (int i = 0; i < Eq; ++i) O[i] = 0.f;
    float m = -INFINITY, lsum = 0.f;

    __shared__ float k_lds[KT][Eq];
    __shared__ float v_lds[KT][Eq];

    const int ntiles = ((qt + 1) * ROWS) / KT;  // causal: keys 0 .. qt*ROWS+127
    for (int t = 0; t < ntiles; ++t) {
        const int s0 = t * KT;
        __syncthreads();
        // cooperative staging: KT*Eq floats each for K and V (512 float4 each)
        {
            const float* kbase = Kp + (((size_t)b * Lq + s0) * Hq + h) * Eq;
            const float* vbase = Vp + (((size_t)b * Lq + s0) * Hq + h) * Eq;
            #pragma unroll
            for (int w = 0; w < (KT * Eq / 4) / ROWS; ++w) {
                int f = threadIdx.x + w * ROWS;  // 0..511
                int j = f >> 4;                  // key row in tile
                int c = f & 15;                  // float4 column
                ((float4*)&k_lds[j][0])[c] = ((const float4*)(kbase + (size_t)j * (Hq * Eq)))[c];
                ((float4*)&v_lds[j][0])[c] = ((const float4*)(vbase + (size_t)j * (Hq * Eq)))[c];
            }
        }
        __syncthreads();

        // scores for this tile (LDS reads are wave-broadcast: same addr all lanes)
        float sc[KT];
        #pragma unroll
        for (int j = 0; j < KT; ++j) {
            float d0 = 0.f, d1 = 0.f, d2 = 0.f, d3 = 0.f;
            #pragma unroll
            for (int e = 0; e < Eq; e += 4) {
                d0 += q[e    ] * k_lds[j][e    ];
                d1 += q[e + 1] * k_lds[j][e + 1];
                d2 += q[e + 2] * k_lds[j][e + 2];
                d3 += q[e + 3] * k_lds[j][e + 3];
            }
            float dot = (d0 + d1) + (d2 + d3);
            sc[j] = (s0 + j <= row) ? dot * scale : -INFINITY;
        }

        // online softmax update
        float tm = m;
        #pragma unroll
        for (int j = 0; j < KT; ++j) tm = fmaxf(tm, sc[j]);
        float alpha = __expf(m - tm);     // m=-inf only on first tile where tm finite -> 0
        float psum = 0.f;
        #pragma unroll
        for (int j = 0; j < KT; ++j) { sc[j] = __expf(sc[j] - tm); psum += sc[j]; }
        #pragma unroll
        for (int e = 0; e < Eq; ++e) O[e] *= alpha;
        #pragma unroll
        for (int j = 0; j < KT; ++j) {
            #pragma unroll
            for (int e = 0; e < Eq; ++e) O[e] += sc[j] * v_lds[j][e];
        }
        m = tm;
        lsum = lsum * alpha + psum;
    }

    const float inv = 1.0f / lsum;
    float* optr = out + (((size_t)b * Lq + row) * Hq + slot) * Eq;
    #pragma unroll
    for (int e = 0; e < Eq; e += 4) {
        float4 o4;
        o4.x = O[e] * inv; o4.y = O[e + 1] * inv;
        o4.z = O[e + 2] * inv; o4.w = O[e + 3] * inv;
        ((float4*)optr)[e / 4] = o4;
    }
}

extern "C" void kernel_launch(void* const* d_in, const int* in_sizes, int n_in,
                              void* d_out, int out_size, void* d_ws, size_t ws_size,
                              hipStream_t stream) {
    const float* queries = (const float*)d_in[0];
    const float* keys    = (const float*)d_in[1];
    const float* keysT   = (const float*)d_in[2];
    const float* values  = (const float*)d_in[3];
    const float* valuesT = (const float*)d_in[4];
    float* out = (float*)d_out;

    dim3 grid(Lq / ROWS, Hq, Bq);   // (q-tiles, head slots, batch)
    dim3 block(ROWS);
    attn_kernel<<<grid, block, 0, stream>>>(queries, keys, keysT, values, valuesT, out);
}

// Round 2
// 168.204 us; speedup vs baseline: 10.1971x; 10.1971x over previous
//
#include <hip/hip_runtime.h>
#include <math.h>

#define Bq 8
#define Lq 1024
#define Hq 8
#define Eq 64
#define QT 64      // q rows per block (16 per wave)
#define KTILE 64   // keys per LDS tile
#define LDW 72     // padded row length in bf16 elems (144 B, 16B-aligned, bank-spread)

// slot -> source head: _PERM=[6,2,1,7,3,0,5,4]; slots 0..6 = series {2,1,7,3,0,5,4}, slot 7 = cross head 6
#define SRC_HEAD_PACKED 0x64503712u

typedef __bf16 bf16x8 __attribute__((ext_vector_type(8)));
typedef float floatx4 __attribute__((ext_vector_type(4)));

__device__ __forceinline__ unsigned short f2bf(float x) {
    union { float f; unsigned u; } v; v.f = x;
    return (unsigned short)((v.u + 0x7FFFu + ((v.u >> 16) & 1u)) >> 16);  // RNE
}

__global__ __launch_bounds__(256, 4)
void attn_mfma(const float* __restrict__ Q, const float* __restrict__ Ks,
               const float* __restrict__ KTs, const float* __restrict__ Vs,
               const float* __restrict__ VTs, float* __restrict__ out) {
    const int qt   = blockIdx.x;      // q-tile (0..15)
    const int slot = blockIdx.y;      // output head slot
    const int b    = blockIdx.z;
    const int h    = (SRC_HEAD_PACKED >> (slot * 4)) & 0xF;
    const float* __restrict__ Kp = (slot == 7) ? KTs : Ks;
    const float* __restrict__ Vp = (slot == 7) ? VTs : Vs;

    const int tid  = threadIdx.x;
    const int wv   = tid >> 6;        // wave 0..3 -> rows wv*16..+15
    const int lane = tid & 63;
    const int ln16 = lane & 15;
    const int quad = lane >> 4;

    __shared__ alignas(16) unsigned short k_lds[KTILE][LDW];
    __shared__ alignas(16) unsigned short vt_lds[Eq][LDW];   // VT[d][k]
    __shared__ alignas(16) unsigned short p_lds[4][16][LDW]; // per-wave P

    // ---- Q fragments, prescaled by 1/sqrt(E) * log2(e) so p = exp2(s - m) ----
    const float qscale = 0.125f * 1.44269504f;
    bf16x8 qf[2];
    {
        const int row = qt * QT + wv * 16 + ln16;
        const float* qp = Q + (((size_t)b * Lq + row) * Hq + h) * Eq + quad * 8;
        #pragma unroll
        for (int ec = 0; ec < 2; ++ec) {
            float4 f0 = ((const float4*)(qp + ec * 32))[0];
            float4 f1 = ((const float4*)(qp + ec * 32))[1];
            union { unsigned short u[8]; bf16x8 v; } t;
            t.u[0] = f2bf(f0.x * qscale); t.u[1] = f2bf(f0.y * qscale);
            t.u[2] = f2bf(f0.z * qscale); t.u[3] = f2bf(f0.w * qscale);
            t.u[4] = f2bf(f1.x * qscale); t.u[5] = f2bf(f1.y * qscale);
            t.u[6] = f2bf(f1.z * qscale); t.u[7] = f2bf(f1.w * qscale);
            qf[ec] = t.v;
        }
    }

    floatx4 O[4];
    #pragma unroll
    for (int i = 0; i < 4; ++i) O[i] = (floatx4){0.f, 0.f, 0.f, 0.f};
    float mrun[4] = {-INFINITY, -INFINITY, -INFINITY, -INFINITY};
    float lrun[4] = {0.f, 0.f, 0.f, 0.f};

    for (int kt = 0; kt <= qt; ++kt) {
        __syncthreads();   // previous iteration's LDS reads done before restage
        // ---- stage K tile: [64 keys][64 e] fp32 -> bf16 row-major ----
        {
            const int j  = tid >> 2;
            const int e0 = (tid & 3) * 16;
            const float* kb = Kp + (((size_t)b * Lq + kt * KTILE + j) * Hq + h) * Eq + e0;
            float4 a0 = ((const float4*)kb)[0];
            float4 a1 = ((const float4*)kb)[1];
            float4 a2 = ((const float4*)kb)[2];
            float4 a3 = ((const float4*)kb)[3];
            union { unsigned short u[8]; bf16x8 v; } t0, t1;
            t0.u[0]=f2bf(a0.x); t0.u[1]=f2bf(a0.y); t0.u[2]=f2bf(a0.z); t0.u[3]=f2bf(a0.w);
            t0.u[4]=f2bf(a1.x); t0.u[5]=f2bf(a1.y); t0.u[6]=f2bf(a1.z); t0.u[7]=f2bf(a1.w);
            t1.u[0]=f2bf(a2.x); t1.u[1]=f2bf(a2.y); t1.u[2]=f2bf(a2.z); t1.u[3]=f2bf(a2.w);
            t1.u[4]=f2bf(a3.x); t1.u[5]=f2bf(a3.y); t1.u[6]=f2bf(a3.z); t1.u[7]=f2bf(a3.w);
            *(bf16x8*)&k_lds[j][e0]     = t0.v;
            *(bf16x8*)&k_lds[j][e0 + 8] = t1.v;
        }
        // ---- stage V tile transposed: VT[d][k] ----
        {
            const int d  = tid & 63;
            const int k0 = (tid >> 6) * 16;
            const float* vb = Vp + (((size_t)b * Lq + kt * KTILE + k0) * Hq + h) * Eq + d;
            float t[16];
            #pragma unroll
            for (int i = 0; i < 16; ++i) t[i] = vb[(size_t)i * (Hq * Eq)];
            union { unsigned short u[8]; bf16x8 v; } t0, t1;
            #pragma unroll
            for (int i = 0; i < 8; ++i) { t0.u[i] = f2bf(t[i]); t1.u[i] = f2bf(t[i + 8]); }
            *(bf16x8*)&vt_lds[d][k0]     = t0.v;
            *(bf16x8*)&vt_lds[d][k0 + 8] = t1.v;
        }
        __syncthreads();

        const bool last = (kt == qt);
        // ---- S = Q K^T (16 rows x 64 keys per wave) ----
        floatx4 s[4];
        #pragma unroll
        for (int nc = 0; nc < 4; ++nc) {
            bf16x8 kf0 = *(const bf16x8*)&k_lds[nc * 16 + ln16][quad * 8];
            bf16x8 kf1 = *(const bf16x8*)&k_lds[nc * 16 + ln16][32 + quad * 8];
            floatx4 acc = (floatx4){0.f, 0.f, 0.f, 0.f};
            acc = __builtin_amdgcn_mfma_f32_16x16x32_bf16(qf[0], kf0, acc, 0, 0, 0);
            acc = __builtin_amdgcn_mfma_f32_16x16x32_bf16(qf[1], kf1, acc, 0, 0, 0);
            s[nc] = acc;
        }
        if (last) {
            const int rl = wv * 16 + quad * 4;
            #pragma unroll
            for (int nc = 0; nc < 4; ++nc)
                #pragma unroll
                for (int r = 0; r < 4; ++r)
                    if (nc * 16 + ln16 > rl + r) s[nc][r] = -INFINITY;
        }
        // ---- online softmax (rows spread as quad*4+reg; cols = 16 lanes) ----
        float mnew[4];
        #pragma unroll
        for (int r = 0; r < 4; ++r)
            mnew[r] = fmaxf(fmaxf(s[0][r], s[1][r]), fmaxf(s[2][r], s[3][r]));
        #pragma unroll
        for (int msk = 1; msk <= 8; msk <<= 1)
            #pragma unroll
            for (int r = 0; r < 4; ++r)
                mnew[r] = fmaxf(mnew[r], __shfl_xor(mnew[r], msk, 64));
        float alpha[4];
        #pragma unroll
        for (int r = 0; r < 4; ++r) {
            mnew[r]  = fmaxf(mnew[r], mrun[r]);
            alpha[r] = __builtin_amdgcn_exp2f(mrun[r] - mnew[r]);
            mrun[r]  = mnew[r];
        }
        float p[4][4], psum[4];
        #pragma unroll
        for (int nc = 0; nc < 4; ++nc)
            #pragma unroll
            for (int r = 0; r < 4; ++r)
                p[nc][r] = __builtin_amdgcn_exp2f(s[nc][r] - mnew[r]);
        #pragma unroll
        for (int r = 0; r < 4; ++r)
            psum[r] = (p[0][r] + p[1][r]) + (p[2][r] + p[3][r]);
        #pragma unroll
        for (int msk = 1; msk <= 8; msk <<= 1)
            #pragma unroll
            for (int r = 0; r < 4; ++r)
                psum[r] += __shfl_xor(psum[r], msk, 64);
        #pragma unroll
        for (int r = 0; r < 4; ++r)
            lrun[r] = lrun[r] * alpha[r] + psum[r];
        #pragma unroll
        for (int dc = 0; dc < 4; ++dc)
            #pragma unroll
            for (int r = 0; r < 4; ++r)
                O[dc][r] *= alpha[r];
        // ---- P: C-layout regs -> LDS (per-wave buffer, same-wave in-order) ----
        #pragma unroll
        for (int nc = 0; nc < 4; ++nc)
            #pragma unroll
            for (int r = 0; r < 4; ++r)
                p_lds[wv][quad * 4 + r][nc * 16 + ln16] = f2bf(p[nc][r]);
        // ---- O += P V ----
        bf16x8 pf0 = *(const bf16x8*)&p_lds[wv][ln16][quad * 8];
        bf16x8 pf1 = *(const bf16x8*)&p_lds[wv][ln16][32 + quad * 8];
        #pragma unroll
        for (int dc = 0; dc < 4; ++dc) {
            bf16x8 vf0 = *(const bf16x8*)&vt_lds[dc * 16 + ln16][quad * 8];
            bf16x8 vf1 = *(const bf16x8*)&vt_lds[dc * 16 + ln16][32 + quad * 8];
            O[dc] = __builtin_amdgcn_mfma_f32_16x16x32_bf16(pf0, vf0, O[dc], 0, 0, 0);
            O[dc] = __builtin_amdgcn_mfma_f32_16x16x32_bf16(pf1, vf1, O[dc], 0, 0, 0);
        }
    }

    // ---- epilogue: O / l, store ----
    float inv[4];
    #pragma unroll
    for (int r = 0; r < 4; ++r) inv[r] = 1.0f / lrun[r];
    const int rowb = qt * QT + wv * 16 + quad * 4;
    #pragma unroll
    for (int dc = 0; dc < 4; ++dc)
        #pragma unroll
        for (int r = 0; r < 4; ++r)
            out[(((size_t)b * Lq + rowb + r) * Hq + slot) * Eq + dc * 16 + ln16] = O[dc][r] * inv[r];
}

extern "C" void kernel_launch(void* const* d_in, const int* in_sizes, int n_in,
                              void* d_out, int out_size, void* d_ws, size_t ws_size,
                              hipStream_t stream) {
    const float* queries = (const float*)d_in[0];
    const float* keys    = (const float*)d_in[1];
    const float* keysT   = (const float*)d_in[2];
    const float* values  = (const float*)d_in[3];
    const float* valuesT = (const float*)d_in[4];
    float* out = (float*)d_out;

    dim3 grid(Lq / QT, Hq, Bq);   // (q-tile, slot, batch)
    dim3 block(256);
    attn_mfma<<<grid, block, 0, stream>>>(queries, keys, keysT, values, valuesT, out);
}

// Round 3
// 144.108 us; speedup vs baseline: 11.9021x; 1.1672x over previous
//
#include <hip/hip_runtime.h>
#include <math.h>

#define Lq 1024
#define Hq 8
#define Eq 64
#define LDW 72   // padded row length (bf16 elems); 144 B rows stay 16B-aligned

// slot -> source head: _PERM=[6,2,1,7,3,0,5,4]; slots 0..6 = series {2,1,7,3,0,5,4}, slot 7 = cross head 6
#define SRC_HEAD_PACKED 0x64503712u

typedef __bf16 bf16_t;
typedef __bf16 bf16x8 __attribute__((ext_vector_type(8)));
typedef __bf16 bf16x4 __attribute__((ext_vector_type(4)));
typedef float floatx4 __attribute__((ext_vector_type(4)));

__device__ __forceinline__ bf16x8 cvt8(const float4 a, const float4 b) {
    bf16x8 r;
    r[0] = (bf16_t)a.x; r[1] = (bf16_t)a.y; r[2] = (bf16_t)a.z; r[3] = (bf16_t)a.w;
    r[4] = (bf16_t)b.x; r[5] = (bf16_t)b.y; r[6] = (bf16_t)b.z; r[7] = (bf16_t)b.w;
    return r;
}

__global__ __launch_bounds__(256, 2)
void attn_mfma(const float* __restrict__ Q, const float* __restrict__ Ks,
               const float* __restrict__ KTs, const float* __restrict__ Vs,
               const float* __restrict__ VTs, float* __restrict__ out) {
    const int p    = blockIdx.x;            // pair index: tiles pA=p (small), pB=15-p (large)
    const int slot = blockIdx.y;
    const int b    = blockIdx.z;
    const int h    = (SRC_HEAD_PACKED >> (slot * 4)) & 0xF;
    const float* __restrict__ Kp = (slot == 7) ? KTs : Ks;
    const float* __restrict__ Vp = (slot == 7) ? VTs : Vs;
    const int pA = p, pB = 15 - p;

    const int tid  = threadIdx.x;
    const int wv   = tid >> 6;
    const int lane = tid & 63;
    const int ln16 = lane & 15;
    const int quad = lane >> 4;

    __shared__ alignas(16) unsigned short k_lds[64][LDW];     // K[key][e]
    __shared__ alignas(16) unsigned short vt_lds[64][LDW];    // V^T[d][key]
    __shared__ alignas(16) unsigned short pt_lds[4][16][LDW]; // per-wave P^T[qrow][key]

    // ---- Q fragments for both q-tiles (B operand: [n=qrow][k=e]); fold scale*log2e ----
    const float qs = 0.125f * 1.44269504f;
    bf16x8 qfA[2], qfB[2];
    {
        const int rA = pA * 64 + wv * 16 + ln16;
        const int rB = pB * 64 + wv * 16 + ln16;
        const float* qa = Q + (((size_t)b * Lq + rA) * Hq + h) * Eq + quad * 8;
        const float* qb = Q + (((size_t)b * Lq + rB) * Hq + h) * Eq + quad * 8;
        #pragma unroll
        for (int ec = 0; ec < 2; ++ec) {
            float4 f0 = ((const float4*)(qa + ec * 32))[0];
            float4 f1 = ((const float4*)(qa + ec * 32))[1];
            float4 g0 = ((const float4*)(qb + ec * 32))[0];
            float4 g1 = ((const float4*)(qb + ec * 32))[1];
            f0.x*=qs; f0.y*=qs; f0.z*=qs; f0.w*=qs; f1.x*=qs; f1.y*=qs; f1.z*=qs; f1.w*=qs;
            g0.x*=qs; g0.y*=qs; g0.z*=qs; g0.w*=qs; g1.x*=qs; g1.y*=qs; g1.z*=qs; g1.w*=qs;
            qfA[ec] = cvt8(f0, f1);
            qfB[ec] = cvt8(g0, g1);
        }
    }

    floatx4 OA[4], OB[4];
    #pragma unroll
    for (int i = 0; i < 4; ++i) { OA[i] = (floatx4){0,0,0,0}; OB[i] = (floatx4){0,0,0,0}; }
    float mA = -INFINITY, lA = 0.f, mB = -INFINITY, lB = 0.f;

    // prefetch registers
    float4 kq[4];
    float  vq[16];
    const int kj = tid >> 2, kc = (tid & 3) * 16;       // K staging: row kj, cols kc..kc+15
    const int vd = tid & 63, vk = (tid >> 6) * 16;      // V staging: dim vd, keys vk..vk+15

    auto load_tile = [&](int kt) {
        const float* kb = Kp + (((size_t)b * Lq + kt * 64 + kj) * Hq + h) * Eq + kc;
        kq[0] = ((const float4*)kb)[0]; kq[1] = ((const float4*)kb)[1];
        kq[2] = ((const float4*)kb)[2]; kq[3] = ((const float4*)kb)[3];
        const float* vb = Vp + (((size_t)b * Lq + kt * 64 + vk) * Hq + h) * Eq + vd;
        #pragma unroll
        for (int i = 0; i < 16; ++i) vq[i] = vb[(size_t)i * (Hq * Eq)];
    };

    auto process = [&](const bf16x8* qf, bf16x8 kf[4][2], bf16x8 vf[4][2],
                       floatx4* O, float& m, float& l, bool diag) {
        // S^T = K Q^T : C-layout col(ln16)=qrow, row(quad*4+r)=key-in-block
        floatx4 s[4];
        #pragma unroll
        for (int nc = 0; nc < 4; ++nc) {
            floatx4 acc = (floatx4){0,0,0,0};
            acc = __builtin_amdgcn_mfma_f32_16x16x32_bf16(kf[nc][0], qf[0], acc, 0, 0, 0);
            acc = __builtin_amdgcn_mfma_f32_16x16x32_bf16(kf[nc][1], qf[1], acc, 0, 0, 0);
            s[nc] = acc;
        }
        if (diag) {
            const int rin = wv * 16 + ln16;
            #pragma unroll
            for (int nc = 0; nc < 4; ++nc)
                #pragma unroll
                for (int r = 0; r < 4; ++r)
                    if (nc * 16 + quad * 4 + r > rin) s[nc][r] = -INFINITY;
        }
        // row max: per-lane over 16 regs, then across quads
        float mn = s[0][0];
        #pragma unroll
        for (int nc = 0; nc < 4; ++nc)
            #pragma unroll
            for (int r = 0; r < 4; ++r) mn = fmaxf(mn, s[nc][r]);
        mn = fmaxf(mn, __shfl_xor(mn, 16, 64));
        mn = fmaxf(mn, __shfl_xor(mn, 32, 64));
        mn = fmaxf(mn, m);
        const float alpha = __builtin_amdgcn_exp2f(m - mn);
        m = mn;
        float ps = 0.f;
        float pv[4][4];
        #pragma unroll
        for (int nc = 0; nc < 4; ++nc)
            #pragma unroll
            for (int r = 0; r < 4; ++r) { pv[nc][r] = __builtin_amdgcn_exp2f(s[nc][r] - mn); ps += pv[nc][r]; }
        ps += __shfl_xor(ps, 16, 64);
        ps += __shfl_xor(ps, 32, 64);
        l = l * alpha + ps;
        #pragma unroll
        for (int dc = 0; dc < 4; ++dc) O[dc] *= alpha;
        // P^T -> per-wave LDS (4 x b64), then read B-frags (2 x b128)
        #pragma unroll
        for (int nc = 0; nc < 4; ++nc) {
            bf16x4 pk;
            pk[0] = (bf16_t)pv[nc][0]; pk[1] = (bf16_t)pv[nc][1];
            pk[2] = (bf16_t)pv[nc][2]; pk[3] = (bf16_t)pv[nc][3];
            *(bf16x4*)&pt_lds[wv][ln16][nc * 16 + quad * 4] = pk;
        }
        bf16x8 pf0 = *(const bf16x8*)&pt_lds[wv][ln16][quad * 8];
        bf16x8 pf1 = *(const bf16x8*)&pt_lds[wv][ln16][32 + quad * 8];
        // O^T += V^T P^T
        #pragma unroll
        for (int dc = 0; dc < 4; ++dc) {
            O[dc] = __builtin_amdgcn_mfma_f32_16x16x32_bf16(vf[dc][0], pf0, O[dc], 0, 0, 0);
            O[dc] = __builtin_amdgcn_mfma_f32_16x16x32_bf16(vf[dc][1], pf1, O[dc], 0, 0, 0);
        }
    };

    load_tile(0);
    for (int kt = 0; kt <= pB; ++kt) {
        __syncthreads();   // all waves done reading previous tile
        // stage current tile (native pk-bf16 converts)
        *(bf16x8*)&k_lds[kj][kc]      = cvt8(kq[0], kq[1]);
        *(bf16x8*)&k_lds[kj][kc + 8]  = cvt8(kq[2], kq[3]);
        {
            const float4* vq4 = (const float4*)vq;
            *(bf16x8*)&vt_lds[vd][vk]     = cvt8(vq4[0], vq4[1]);
            *(bf16x8*)&vt_lds[vd][vk + 8] = cvt8(vq4[2], vq4[3]);
        }
        if (kt < pB) load_tile(kt + 1);   // prefetch overlaps with compute below
        __syncthreads();

        // shared fragment reads (used by both q-sets)
        bf16x8 kf[4][2], vf[4][2];
        #pragma unroll
        for (int c = 0; c < 4; ++c) {
            kf[c][0] = *(const bf16x8*)&k_lds[c * 16 + ln16][quad * 8];
            kf[c][1] = *(const bf16x8*)&k_lds[c * 16 + ln16][32 + quad * 8];
            vf[c][0] = *(const bf16x8*)&vt_lds[c * 16 + ln16][quad * 8];
            vf[c][1] = *(const bf16x8*)&vt_lds[c * 16 + ln16][32 + quad * 8];
        }
        if (kt <= pA) process(qfA, kf, vf, OA, mA, lA, kt == pA);
        process(qfB, kf, vf, OB, mB, lB, kt == pB);
    }

    // ---- epilogue: O^T lane layout: qrow=ln16(+base), d = dc*16 + quad*4 + r ----
    {
        const float inv = 1.0f / lA;
        const int row = pA * 64 + wv * 16 + ln16;
        float* op = out + (((size_t)b * Lq + row) * Hq + slot) * Eq + quad * 4;
        #pragma unroll
        for (int dc = 0; dc < 4; ++dc) {
            float4 o; o.x = OA[dc][0] * inv; o.y = OA[dc][1] * inv;
            o.z = OA[dc][2] * inv; o.w = OA[dc][3] * inv;
            *(float4*)(op + dc * 16) = o;
        }
    }
    {
        const float inv = 1.0f / lB;
        const int row = pB * 64 + wv * 16 + ln16;
        float* op = out + (((size_t)b * Lq + row) * Hq + slot) * Eq + quad * 4;
        #pragma unroll
        for (int dc = 0; dc < 4; ++dc) {
            float4 o; o.x = OB[dc][0] * inv; o.y = OB[dc][1] * inv;
            o.z = OB[dc][2] * inv; o.w = OB[dc][3] * inv;
            *(float4*)(op + dc * 16) = o;
        }
    }
}

extern "C" void kernel_launch(void* const* d_in, const int* in_sizes, int n_in,
                              void* d_out, int out_size, void* d_ws, size_t ws_size,
                              hipStream_t stream) {
    const float* queries = (const float*)d_in[0];
    const float* keys    = (const float*)d_in[1];
    const float* keysT   = (const float*)d_in[2];
    const float* values  = (const float*)d_in[3];
    const float* valuesT = (const float*)d_in[4];
    float* out = (float*)d_out;

    dim3 grid(8, Hq, 8);   // (pair, slot, batch)
    dim3 block(256);
    attn_mfma<<<grid, block, 0, stream>>>(queries, keys, keysT, values, valuesT, out);
}